// Round 12
// baseline (44615.326 us; speedup 1.0000x reference)
//
#include <hip/hip_runtime.h>
#include <cstdint>
#include <cstddef>

#define H        2048
#define T_STEPS  16384
#define G        256     // workgroups == CUs, 1 WG/CU
#define HC       8       // h indices per WG (H/G)
#define WGSIZE   256
#define NREP     8       // mailbox replicas: reader WG g polls replica g&7

// ---- LDS layout (bytes): weights in VGPRs, samples in LDS, no h16 buffer ----
#define LDS_S_OFF    0                         // float2 samples[16384] = 128KB
#define LDS_RED_OFF  131072                    // float red[8]
#define LDS_BYTES    (131072 + 32)             // 131104 < 160KB

typedef unsigned long long ull;
typedef unsigned int uv4 __attribute__((ext_vector_type(4)));
typedef _Float16 half2_ __attribute__((ext_vector_type(2)));

__device__ __forceinline__ float sigmoidf_(float x) {
    return 1.0f / (1.0f + __expf(-x));
}
__device__ __forceinline__ float tanhf_(float x) {
    return 1.0f - 2.0f / (__expf(2.0f * x) + 1.0f);
}
__device__ __forceinline__ uint32_t pack_f16x2(float a, float b) {
    _Float16 ha = (_Float16)a, hb = (_Float16)b;
    return (uint32_t)__builtin_bit_cast(uint16_t, ha)
         | ((uint32_t)__builtin_bit_cast(uint16_t, hb) << 16);
}
__device__ __forceinline__ float f16lo(uint32_t d) {
    return (float)__builtin_bit_cast(_Float16, (uint16_t)(d & 0xFFFFu));
}
__device__ __forceinline__ float f16hi(uint32_t d) {
    return (float)__builtin_bit_cast(_Float16, (uint16_t)(d >> 16));
}
__device__ __forceinline__ float dot2f(uint32_t w, uint32_t h, float acc) {
#if __has_builtin(__builtin_amdgcn_fdot2)
    return __builtin_amdgcn_fdot2(__builtin_bit_cast(half2_, w),
                                  __builtin_bit_cast(half2_, h), acc, false);
#else
    return acc + f16lo(w) * f16lo(h) + f16hi(w) * f16hi(h);
#endif
}

// ---- DPP wave-sum (rocPRIM pattern): 6 VALU adds, total lands in lane 63 ----
template <int CTRL, int ROW_MASK>
__device__ __forceinline__ float dpp_add(float x) {
    int xi = __builtin_bit_cast(int, x);
    int s  = __builtin_amdgcn_update_dpp(0, xi, CTRL, ROW_MASK, 0xf, true);
    return x + __builtin_bit_cast(float, s);
}
__device__ __forceinline__ float wave_sum_dpp(float x) {
    x = dpp_add<0x111, 0xf>(x);   // row_shr:1
    x = dpp_add<0x112, 0xf>(x);   // row_shr:2
    x = dpp_add<0x114, 0xf>(x);   // row_shr:4
    x = dpp_add<0x118, 0xf>(x);   // row_shr:8  -> lane15/31/47/63 = row sums
    x = dpp_add<0x142, 0xa>(x);   // row_bcast:15 -> lane31=r0+r1, lane63=r2+r3
    x = dpp_add<0x143, 0xc>(x);   // row_bcast:31 -> lane63 = total
    return x;
}
__device__ __forceinline__ float rl63(float x) {
    return __builtin_bit_cast(float,
        __builtin_amdgcn_readlane(__builtin_bit_cast(int, x), 63));
}
// fold of (tag ^ tu) over the 16 tag words of one 8-load poll round
__device__ __forceinline__ uint32_t tagfold(uv4 a, uv4 b, uv4 c, uv4 d,
                                            uv4 e, uv4 f, uv4 g2, uv4 h2,
                                            uint32_t tu) {
    return (a.y ^ tu) | (a.w ^ tu) | (b.y ^ tu) | (b.w ^ tu)
         | (c.y ^ tu) | (c.w ^ tu) | (d.y ^ tu) | (d.w ^ tu)
         | (e.y ^ tu) | (e.w ^ tu) | (f.y ^ tu) | (f.w ^ tu)
         | (g2.y ^ tu) | (g2.w ^ tu) | (h2.y ^ tu) | (h2.w ^ tu);
}

// hrep layout: [8 replicas][2 parities][1024 slots of {f16x2, u32 tag}] = 128KB
__global__ void init_hrep_kernel(ull* __restrict__ hl) {
    int i = blockIdx.x * 256 + threadIdx.x;            // 0..16383
    int parity = (i >> 10) & 1;
    ull v = (parity == 0) ? 0ull : 0xFFFFFFFF00000000ull;
    __hip_atomic_store(hl + i, v, __ATOMIC_RELAXED, __HIP_MEMORY_SCOPE_AGENT);
}

extern "C" __global__ void __launch_bounds__(WGSIZE, 1)
gru_persistent_kernel(const float* __restrict__ samples,
                      const float* __restrict__ w_ih,
                      const float* __restrict__ w_hh,
                      const float* __restrict__ b_ih,
                      const float* __restrict__ b_hh,
                      const float* __restrict__ fc_w,
                      const float* __restrict__ fc_b,
                      float* __restrict__ out,
                      ull*   __restrict__ hrep)    // [8][2][1024] tagged slots
{
    extern __shared__ char smem[];
    float2*   slds = (float2*)(smem + LDS_S_OFF);      // samples, LDS-resident
    float*    red  = (float*)(smem + LDS_RED_OFF);

    const int g    = blockIdx.x;
    const int tid  = threadIdx.x;
    const int wave = tid >> 6;
    const int lane = tid & 63;
    const int myrep = g & (NREP - 1);   // the replica this WG reads

    // ---- one-time: stage this wave's 6 w_hh rows into VGPRs as f16x2 ----
    uint4 wreg[6][4];
    float4 creg[6];                     // (w_ih0, w_ih1, b_ih, b_hh) per row
#pragma unroll
    for (int qi = 0; qi < 6; ++qi) {
        const int grow = (qi >> 1) * H + g * HC + 2 * wave + (qi & 1);
        const float* wr = w_hh + (size_t)grow * H;
#pragma unroll
        for (int k = 0; k < 4; ++k) {
            const float* s2 = wr + 8 * (lane + 64 * k);
            float4 a = *(const float4*)(s2);
            float4 b = *(const float4*)(s2 + 4);
            uint4 p;
            p.x = pack_f16x2(a.x, a.y);
            p.y = pack_f16x2(a.z, a.w);
            p.z = pack_f16x2(b.x, b.y);
            p.w = pack_f16x2(b.z, b.w);
            wreg[qi][k] = p;
        }
        creg[qi] = make_float4(w_ih[grow * 2 + 0], w_ih[grow * 2 + 1],
                               b_ih[grow], b_hh[grow]);
    }
    {   // one-time: samples -> LDS
        const float4* s4 = (const float4*)samples;
        float4* d4 = (float4*)slds;
        for (int i = tid; i < T_STEPS / 2; i += WGSIZE) d4[i] = s4[i];
    }
    __syncthreads();

    // publish targets: lanes 0-7 each own one replica (single instruction)
    ull* pub_e = hrep + ((size_t)(2 * (lane & 7) + 0) << 10) + g * 4 + wave;  // pn=0
    ull* pub_o = hrep + ((size_t)(2 * (lane & 7) + 1) << 10) + g * 4 + wave;  // pn=1

    // per-parity direct-poll bases: lane's 4 chunks at {0,16,2048,2064} from
    // base and base+4096 (chunk k at lane*32 + k*2048)
    const char* pbase0 = (const char*)(hrep + ((size_t)(myrep * 2 + 0) << 10)) + lane * 32;
    const char* pbase1 = (const char*)(hrep + ((size_t)(myrep * 2 + 1) << 10)) + lane * 32;

    float hloc0 = 0.0f, hloc1 = 0.0f;

    // ---- adaptive pre-poll sleep controller (R12) ----
    // Model: first poll's memory-side snapshot must land AFTER publish-commit
    // readiness or the step pays a full extra poll round (~1000 cy).  The knee
    // is unknown and drifts (clock throttling), and s_sleep only takes an
    // immediate -> sleep nsl notches of 256 cy in a loop.  On a multi-round
    // step: nsl += 2; after 8 consecutive 1-round steps: nsl -= 1.  Asymmetry
    // + hysteresis parks each WG ~1 notch above its knee (~256 cy overshoot
    // traded against the ~1000 cy miss round).
    int nsl = 5;        // 1280 cy initial (= R11's fixed sleep)
    int ok_run = 0;

    for (int t = 0; t < T_STEPS; ++t) {
        float2 sv = slds[t];
        const int p = t & 1;

        if (t > 0) {
            for (int i = 0; i < nsl; ++i) __builtin_amdgcn_s_sleep(4);
        }

        // ---- single-round direct 4-chunk poll (R8 structure, verbatim):
        // vmcnt(0) inside the loop -> no in-flight loads survive (no race).
        const char* pb  = p ? pbase1 : pbase0;
        const char* pb2 = pb + 4096;
        const uint32_t tu = (uint32_t)t;
        uv4 c0a, c0b, c1a, c1b, c2a, c2b, c3a, c3b;
        int rounds = 0;
        for (;;) {
            asm volatile(
                "global_load_dwordx4 %0, %8, off sc0 sc1\n\t"
                "global_load_dwordx4 %1, %8, off offset:16 sc0 sc1\n\t"
                "global_load_dwordx4 %2, %8, off offset:2048 sc0 sc1\n\t"
                "global_load_dwordx4 %3, %8, off offset:2064 sc0 sc1\n\t"
                "global_load_dwordx4 %4, %9, off sc0 sc1\n\t"
                "global_load_dwordx4 %5, %9, off offset:16 sc0 sc1\n\t"
                "global_load_dwordx4 %6, %9, off offset:2048 sc0 sc1\n\t"
                "global_load_dwordx4 %7, %9, off offset:2064 sc0 sc1\n\t"
                "s_waitcnt vmcnt(0)"
                : "=v"(c0a), "=v"(c0b), "=v"(c1a), "=v"(c1b),
                  "=v"(c2a), "=v"(c2b), "=v"(c3a), "=v"(c3b)
                : "v"(pb), "v"(pb2)
                : "memory");
            ++rounds;
            uint32_t m = tagfold(c0a, c0b, c1a, c1b, c2a, c2b, c3a, c3b, tu);
            if (m == 0) break;
        }
        // assemble the 4 h-chunks (strip tags: payloads at .x/.z)
        uint4 hq[4];
        hq[0].x = c0a.x; hq[0].y = c0a.z; hq[0].z = c0b.x; hq[0].w = c0b.z;
        hq[1].x = c1a.x; hq[1].y = c1a.z; hq[1].z = c1b.x; hq[1].w = c1b.z;
        hq[2].x = c2a.x; hq[2].y = c2a.z; hq[2].z = c2b.x; hq[2].w = c2b.z;
        hq[3].x = c3a.x; hq[3].y = c3a.z; hq[3].z = c3b.x; hq[3].w = c3b.z;

        float acc[6];
#pragma unroll
        for (int qi = 0; qi < 6; ++qi) {
            float s = 0.0f;
#pragma unroll
            for (int k = 0; k < 4; ++k) {
                const uint4 wv = wreg[qi][k];
                s = dot2f(wv.x, hq[k].x, s);
                s = dot2f(wv.y, hq[k].y, s);
                s = dot2f(wv.z, hq[k].z, s);
                s = dot2f(wv.w, hq[k].w, s);
            }
            acc[qi] = s;
        }

        // ---- DPP reduction: 6 independent 6-op trees (ILP) ----
        float t0 = rl63(wave_sum_dpp(acc[0]));
        float t1 = rl63(wave_sum_dpp(acc[1]));
        float t2 = rl63(wave_sum_dpp(acc[2]));
        float t3 = rl63(wave_sum_dpp(acc[3]));
        float t4 = rl63(wave_sum_dpp(acc[4]));
        float t5 = rl63(wave_sum_dpp(acc[5]));

        // gate tail split across lanes 0/1 (jj = lane); sums are SGPR-uniform
        const bool l0 = (lane == 0);
        float aR = l0 ? t0 : t1;
        float aZ = l0 ? t2 : t3;
        float aN = l0 ? t4 : t5;
        float4 cr = l0 ? creg[0] : creg[1];
        float4 cz = l0 ? creg[2] : creg[3];
        float4 cn = l0 ? creg[4] : creg[5];
        float hold = l0 ? hloc0 : hloc1;
        float xr = sv.x * cr.x + sv.y * cr.y + cr.z;
        float xz = sv.x * cz.x + sv.y * cz.y + cz.z;
        float xn = sv.x * cn.x + sv.y * cn.y + cn.z;
        float r  = sigmoidf_(xr + aR + cr.w);
        float z  = sigmoidf_(xz + aZ + cz.w);
        float n  = tanhf_(xn + r * (aN + cn.w));
        float hn = (1.0f - z) * n + z * hold;    // meaningful in lanes 0,1

        float h0n = __shfl(hn, 0, 64);
        float h1n = __shfl(hn, 1, 64);
        hloc0 = h0n;
        hloc1 = h1n;

        // publish: one agent-scope atomic per replica, lanes 0-7 in parallel
        ull s0 = (ull)pack_f16x2(h0n, h1n) | ((ull)(uint32_t)(t + 1) << 32);
        const int pn = (t + 1) & 1;
        if (lane < 8) {
            ull* pp = pn ? pub_o : pub_e;
            (void)__hip_atomic_exchange(pp, s0, __ATOMIC_RELAXED,
                                        __HIP_MEMORY_SCOPE_AGENT);
        }

        // controller update (SALU, off the critical chain, after publish)
        const bool multi = __any((int)(rounds > 1));
        if (multi) {
            nsl = (nsl + 2 > 16) ? 16 : nsl + 2;
            ok_run = 0;
        } else if (++ok_run >= 8) {
            nsl = (nsl - 1 < 3) ? 3 : nsl - 1;
            ok_run = 0;
        }
        // no barrier anywhere in the step loop
    }

    // ---- epilogue: WG 0 computes sigmoid(h_T . fc_w + fc_b) ----
    if (g == 0) {
        const ull* lp = hrep + ((size_t)(T_STEPS & 1) << 10) + tid * 4;  // replica 0
        const uint32_t tu = (uint32_t)T_STEPS;
        uv4 q0, q1;
        for (;;) {
            asm volatile(
                "global_load_dwordx4 %0, %2, off sc0 sc1\n\t"
                "global_load_dwordx4 %1, %2, off offset:16 sc0 sc1\n\t"
                "s_waitcnt vmcnt(0)"
                : "=v"(q0), "=v"(q1)
                : "v"(lp)
                : "memory");
            if ((q0.y == tu) & (q0.w == tu) & (q1.y == tu) & (q1.w == tu)) break;
            __builtin_amdgcn_s_sleep(2);
        }
        float hv[8];
        hv[0] = f16lo(q0.x); hv[1] = f16hi(q0.x);
        hv[2] = f16lo(q0.z); hv[3] = f16hi(q0.z);
        hv[4] = f16lo(q1.x); hv[5] = f16hi(q1.x);
        hv[6] = f16lo(q1.z); hv[7] = f16hi(q1.z);
        float pacc = 0.0f;
#pragma unroll
        for (int e = 0; e < 8; ++e)
            pacc += hv[e] * fc_w[tid * 8 + e];
#pragma unroll
        for (int off = 32; off > 0; off >>= 1)
            pacc += __shfl_xor(pacc, off, 64);
        if (lane == 0) red[wave] = pacc;
        __syncthreads();
        if (tid == 0) {
            float s = red[0] + red[1] + red[2] + red[3];
            out[0] = sigmoidf_(s + fc_b[0]);
        }
    }
}

extern "C" void kernel_launch(void* const* d_in, const int* in_sizes, int n_in,
                              void* d_out, int out_size, void* d_ws, size_t ws_size,
                              hipStream_t stream) {
    const float* samples = (const float*)d_in[0];
    const float* w_ih    = (const float*)d_in[1];
    const float* w_hh    = (const float*)d_in[2];
    const float* b_ih    = (const float*)d_in[3];
    const float* b_hh    = (const float*)d_in[4];
    const float* fc_w    = (const float*)d_in[5];
    const float* fc_b    = (const float*)d_in[6];
    float* out  = (float*)d_out;
    ull*   hrep = (ull*)d_ws;    // [8][2][1024] tagged slots = 128KB

    // seed every replica: parity-0 = h0 (zeros, tag 0); parity-1 = sentinel
    hipLaunchKernelGGL(init_hrep_kernel, dim3(64), dim3(256), 0, stream, hrep);

    (void)hipFuncSetAttribute((const void*)gru_persistent_kernel,
                              hipFuncAttributeMaxDynamicSharedMemorySize, LDS_BYTES);

    void* args[] = {(void*)&samples, (void*)&w_ih, (void*)&w_hh, (void*)&b_ih,
                    (void*)&b_hh, (void*)&fc_w, (void*)&fc_b,
                    (void*)&out, (void*)&hrep};
    hipError_t rc = hipLaunchCooperativeKernel(
        reinterpret_cast<void*>(gru_persistent_kernel),
        dim3(G), dim3(WGSIZE), args, LDS_BYTES, stream);
    if (rc != hipSuccess) {
        hipLaunchKernelGGL(gru_persistent_kernel, dim3(G), dim3(WGSIZE), LDS_BYTES, stream,
                           samples, w_ih, w_hh, b_ih, b_hh, fc_w, fc_b, out, hrep);
    }
}

// Round 13
// 29351.166 us; speedup vs baseline: 1.5201x; 1.5201x over previous
//
#include <hip/hip_runtime.h>
#include <cstdint>
#include <cstddef>

#define H        2048
#define T_STEPS  16384
#define G        256     // workgroups == CUs, 1 WG/CU
#define HC       8       // h indices per WG (H/G)
#define WGSIZE   256
#define NREP     8       // mailbox replicas: reader WG g polls replica g&7

// ---- LDS layout (bytes): weights in VGPRs, samples in LDS, no h16 buffer ----
#define LDS_S_OFF    0                         // float2 samples[16384] = 128KB
#define LDS_RED_OFF  131072                    // float red[8]
#define LDS_BYTES    (131072 + 32)             // 131104 < 160KB

typedef unsigned long long ull;
typedef unsigned int uv4 __attribute__((ext_vector_type(4)));
typedef _Float16 half2_ __attribute__((ext_vector_type(2)));

__device__ __forceinline__ float sigmoidf_(float x) {
    return 1.0f / (1.0f + __expf(-x));
}
__device__ __forceinline__ float tanhf_(float x) {
    return 1.0f - 2.0f / (__expf(2.0f * x) + 1.0f);
}
__device__ __forceinline__ uint32_t pack_f16x2(float a, float b) {
    _Float16 ha = (_Float16)a, hb = (_Float16)b;
    return (uint32_t)__builtin_bit_cast(uint16_t, ha)
         | ((uint32_t)__builtin_bit_cast(uint16_t, hb) << 16);
}
__device__ __forceinline__ float f16lo(uint32_t d) {
    return (float)__builtin_bit_cast(_Float16, (uint16_t)(d & 0xFFFFu));
}
__device__ __forceinline__ float f16hi(uint32_t d) {
    return (float)__builtin_bit_cast(_Float16, (uint16_t)(d >> 16));
}
__device__ __forceinline__ float dot2f(uint32_t w, uint32_t h, float acc) {
#if __has_builtin(__builtin_amdgcn_fdot2)
    return __builtin_amdgcn_fdot2(__builtin_bit_cast(half2_, w),
                                  __builtin_bit_cast(half2_, h), acc, false);
#else
    return acc + f16lo(w) * f16lo(h) + f16hi(w) * f16hi(h);
#endif
}

// ---- DPP wave-sum (rocPRIM pattern): 6 VALU adds, total lands in lane 63 ----
template <int CTRL, int ROW_MASK>
__device__ __forceinline__ float dpp_add(float x) {
    int xi = __builtin_bit_cast(int, x);
    int s  = __builtin_amdgcn_update_dpp(0, xi, CTRL, ROW_MASK, 0xf, true);
    return x + __builtin_bit_cast(float, s);
}
__device__ __forceinline__ float wave_sum_dpp(float x) {
    x = dpp_add<0x111, 0xf>(x);   // row_shr:1
    x = dpp_add<0x112, 0xf>(x);   // row_shr:2
    x = dpp_add<0x114, 0xf>(x);   // row_shr:4
    x = dpp_add<0x118, 0xf>(x);   // row_shr:8  -> lane15/31/47/63 = row sums
    x = dpp_add<0x142, 0xa>(x);   // row_bcast:15 -> lane31=r0+r1, lane63=r2+r3
    x = dpp_add<0x143, 0xc>(x);   // row_bcast:31 -> lane63 = total
    return x;
}
__device__ __forceinline__ float rl63(float x) {
    return __builtin_bit_cast(float,
        __builtin_amdgcn_readlane(__builtin_bit_cast(int, x), 63));
}
__device__ __forceinline__ float rlN(float x, int n) {
    return __builtin_bit_cast(float,
        __builtin_amdgcn_readlane(__builtin_bit_cast(int, x), n));
}
// fold of (tag ^ tu) over the 16 tag words of one 8-load poll round
__device__ __forceinline__ uint32_t tagfold(uv4 a, uv4 b, uv4 c, uv4 d,
                                            uv4 e, uv4 f, uv4 g2, uv4 h2,
                                            uint32_t tu) {
    return (a.y ^ tu) | (a.w ^ tu) | (b.y ^ tu) | (b.w ^ tu)
         | (c.y ^ tu) | (c.w ^ tu) | (d.y ^ tu) | (d.w ^ tu)
         | (e.y ^ tu) | (e.w ^ tu) | (f.y ^ tu) | (f.w ^ tu)
         | (g2.y ^ tu) | (g2.w ^ tu) | (h2.y ^ tu) | (h2.w ^ tu);
}

// hrep layout: [8 replicas][2 parities][1024 slots of {f16x2, u32 tag}] = 128KB
__global__ void init_hrep_kernel(ull* __restrict__ hl) {
    int i = blockIdx.x * 256 + threadIdx.x;            // 0..16383
    int parity = (i >> 10) & 1;
    ull v = (parity == 0) ? 0ull : 0xFFFFFFFF00000000ull;
    __hip_atomic_store(hl + i, v, __ATOMIC_RELAXED, __HIP_MEMORY_SCOPE_AGENT);
}

extern "C" __global__ void __launch_bounds__(WGSIZE, 1)
gru_persistent_kernel(const float* __restrict__ samples,
                      const float* __restrict__ w_ih,
                      const float* __restrict__ w_hh,
                      const float* __restrict__ b_ih,
                      const float* __restrict__ b_hh,
                      const float* __restrict__ fc_w,
                      const float* __restrict__ fc_b,
                      float* __restrict__ out,
                      ull*   __restrict__ hrep)    // [8][2][1024] tagged slots
{
    extern __shared__ char smem[];
    float2*   slds = (float2*)(smem + LDS_S_OFF);      // samples, LDS-resident
    float*    red  = (float*)(smem + LDS_RED_OFF);

    const int g    = blockIdx.x;
    const int tid  = threadIdx.x;
    const int wave = tid >> 6;
    const int lane = tid & 63;
    const int myrep = g & (NREP - 1);   // the replica this WG reads

    // ---- one-time: stage this wave's 6 w_hh rows into VGPRs as f16x2 ----
    uint4 wreg[6][4];
    float4 creg[6];                     // (w_ih0, w_ih1, b_ih, b_hh) per row
#pragma unroll
    for (int qi = 0; qi < 6; ++qi) {
        const int grow = (qi >> 1) * H + g * HC + 2 * wave + (qi & 1);
        const float* wr = w_hh + (size_t)grow * H;
#pragma unroll
        for (int k = 0; k < 4; ++k) {
            const float* s2 = wr + 8 * (lane + 64 * k);
            float4 a = *(const float4*)(s2);
            float4 b = *(const float4*)(s2 + 4);
            uint4 p;
            p.x = pack_f16x2(a.x, a.y);
            p.y = pack_f16x2(a.z, a.w);
            p.z = pack_f16x2(b.x, b.y);
            p.w = pack_f16x2(b.z, b.w);
            wreg[qi][k] = p;
        }
        creg[qi] = make_float4(w_ih[grow * 2 + 0], w_ih[grow * 2 + 1],
                               b_ih[grow], b_hh[grow]);
    }
    {   // one-time: samples -> LDS
        const float4* s4 = (const float4*)samples;
        float4* d4 = (float4*)slds;
        for (int i = tid; i < T_STEPS / 2; i += WGSIZE) d4[i] = s4[i];
    }
    __syncthreads();

    // publish targets: lanes 0-7 each own one replica (single instruction)
    ull* pub_e = hrep + ((size_t)(2 * (lane & 7) + 0) << 10) + g * 4 + wave;  // pn=0
    ull* pub_o = hrep + ((size_t)(2 * (lane & 7) + 1) << 10) + g * 4 + wave;  // pn=1

    // per-parity direct-poll bases: lane's 4 chunks at {0,16,2048,2064} from
    // base and base+4096 (chunk k at lane*32 + k*2048)
    const char* pbase0 = (const char*)(hrep + ((size_t)(myrep * 2 + 0) << 10)) + lane * 32;
    const char* pbase1 = (const char*)(hrep + ((size_t)(myrep * 2 + 1) << 10)) + lane * 32;

    float hloc0 = 0.0f, hloc1 = 0.0f;

    for (int t = 0; t < T_STEPS; ++t) {
        float2 sv = slds[t];
        const int p = t & 1;

        // FIXED pre-poll sleep, 26 notches (~1664 cy).  R12 lesson: adaptive
        // per-WG control is unstable (coupled agents ratchet each other's
        // sleep to the cap) -- open-loop fixed timing only.  26 chosen from
        // the R8/R11 interpolation: sleep 20 (R11) pays a ~full miss round
        // (disc ~1846 cy); sleep 24 at slower compute paid ~1460; with DPP's
        // earlier publish, 26 should make most steps single-round.
        if (t > 0) __builtin_amdgcn_s_sleep(26);

        // ---- single-round direct 4-chunk poll (R8 structure, verbatim):
        // vmcnt(0) inside the loop -> no in-flight loads survive (no race).
        const char* pb  = p ? pbase1 : pbase0;
        const char* pb2 = pb + 4096;
        const uint32_t tu = (uint32_t)t;
        uv4 c0a, c0b, c1a, c1b, c2a, c2b, c3a, c3b;
        for (;;) {
            asm volatile(
                "global_load_dwordx4 %0, %8, off sc0 sc1\n\t"
                "global_load_dwordx4 %1, %8, off offset:16 sc0 sc1\n\t"
                "global_load_dwordx4 %2, %8, off offset:2048 sc0 sc1\n\t"
                "global_load_dwordx4 %3, %8, off offset:2064 sc0 sc1\n\t"
                "global_load_dwordx4 %4, %9, off sc0 sc1\n\t"
                "global_load_dwordx4 %5, %9, off offset:16 sc0 sc1\n\t"
                "global_load_dwordx4 %6, %9, off offset:2048 sc0 sc1\n\t"
                "global_load_dwordx4 %7, %9, off offset:2064 sc0 sc1\n\t"
                "s_waitcnt vmcnt(0)"
                : "=v"(c0a), "=v"(c0b), "=v"(c1a), "=v"(c1b),
                  "=v"(c2a), "=v"(c2b), "=v"(c3a), "=v"(c3b)
                : "v"(pb), "v"(pb2)
                : "memory");
            uint32_t m = tagfold(c0a, c0b, c1a, c1b, c2a, c2b, c3a, c3b, tu);
            if (m == 0) break;
        }
        // assemble the 4 h-chunks (strip tags: payloads at .x/.z)
        uint4 hq[4];
        hq[0].x = c0a.x; hq[0].y = c0a.z; hq[0].z = c0b.x; hq[0].w = c0b.z;
        hq[1].x = c1a.x; hq[1].y = c1a.z; hq[1].z = c1b.x; hq[1].w = c1b.z;
        hq[2].x = c2a.x; hq[2].y = c2a.z; hq[2].z = c2b.x; hq[2].w = c2b.z;
        hq[3].x = c3a.x; hq[3].y = c3a.z; hq[3].z = c3b.x; hq[3].w = c3b.z;

        float acc[6];
#pragma unroll
        for (int qi = 0; qi < 6; ++qi) {
            float s = 0.0f;
#pragma unroll
            for (int k = 0; k < 4; ++k) {
                const uint4 wv = wreg[qi][k];
                s = dot2f(wv.x, hq[k].x, s);
                s = dot2f(wv.y, hq[k].y, s);
                s = dot2f(wv.z, hq[k].z, s);
                s = dot2f(wv.w, hq[k].w, s);
            }
            acc[qi] = s;
        }

        // ---- DPP reduction: 6 independent 6-op trees (ILP) ----
        float t0 = rl63(wave_sum_dpp(acc[0]));
        float t1 = rl63(wave_sum_dpp(acc[1]));
        float t2 = rl63(wave_sum_dpp(acc[2]));
        float t3 = rl63(wave_sum_dpp(acc[3]));
        float t4 = rl63(wave_sum_dpp(acc[4]));
        float t5 = rl63(wave_sum_dpp(acc[5]));

        // gate tail split across lanes 0/1 (jj = lane); sums are SGPR-uniform
        const bool l0 = (lane == 0);
        float aR = l0 ? t0 : t1;
        float aZ = l0 ? t2 : t3;
        float aN = l0 ? t4 : t5;
        float4 cr = l0 ? creg[0] : creg[1];
        float4 cz = l0 ? creg[2] : creg[3];
        float4 cn = l0 ? creg[4] : creg[5];
        float hold = l0 ? hloc0 : hloc1;
        float xr = sv.x * cr.x + sv.y * cr.y + cr.z;
        float xz = sv.x * cz.x + sv.y * cz.y + cz.z;
        float xn = sv.x * cn.x + sv.y * cn.y + cn.z;
        float r  = sigmoidf_(xr + aR + cr.w);
        float z  = sigmoidf_(xz + aZ + cz.w);
        float n  = tanhf_(xn + r * (aN + cn.w));
        float hn = (1.0f - z) * n + z * hold;    // meaningful in lanes 0,1

        // SALU broadcast (readlane) instead of shfl: off the VALU crossbar
        float h0n = rlN(hn, 0);
        float h1n = rlN(hn, 1);
        hloc0 = h0n;
        hloc1 = h1n;

        // publish: one agent-scope atomic per replica, lanes 0-7 in parallel
        ull s0 = (ull)pack_f16x2(h0n, h1n) | ((ull)(uint32_t)(t + 1) << 32);
        const int pn = (t + 1) & 1;
        if (lane < 8) {
            ull* pp = pn ? pub_o : pub_e;
            (void)__hip_atomic_exchange(pp, s0, __ATOMIC_RELAXED,
                                        __HIP_MEMORY_SCOPE_AGENT);
        }
        // no barrier anywhere in the step loop
    }

    // ---- epilogue: WG 0 computes sigmoid(h_T . fc_w + fc_b) ----
    if (g == 0) {
        const ull* lp = hrep + ((size_t)(T_STEPS & 1) << 10) + tid * 4;  // replica 0
        const uint32_t tu = (uint32_t)T_STEPS;
        uv4 q0, q1;
        for (;;) {
            asm volatile(
                "global_load_dwordx4 %0, %2, off sc0 sc1\n\t"
                "global_load_dwordx4 %1, %2, off offset:16 sc0 sc1\n\t"
                "s_waitcnt vmcnt(0)"
                : "=v"(q0), "=v"(q1)
                : "v"(lp)
                : "memory");
            if ((q0.y == tu) & (q0.w == tu) & (q1.y == tu) & (q1.w == tu)) break;
            __builtin_amdgcn_s_sleep(2);
        }
        float hv[8];
        hv[0] = f16lo(q0.x); hv[1] = f16hi(q0.x);
        hv[2] = f16lo(q0.z); hv[3] = f16hi(q0.z);
        hv[4] = f16lo(q1.x); hv[5] = f16hi(q1.x);
        hv[6] = f16lo(q1.z); hv[7] = f16hi(q1.z);
        float pacc = 0.0f;
#pragma unroll
        for (int e = 0; e < 8; ++e)
            pacc += hv[e] * fc_w[tid * 8 + e];
#pragma unroll
        for (int off = 32; off > 0; off >>= 1)
            pacc += __shfl_xor(pacc, off, 64);
        if (lane == 0) red[wave] = pacc;
        __syncthreads();
        if (tid == 0) {
            float s = red[0] + red[1] + red[2] + red[3];
            out[0] = sigmoidf_(s + fc_b[0]);
        }
    }
}

extern "C" void kernel_launch(void* const* d_in, const int* in_sizes, int n_in,
                              void* d_out, int out_size, void* d_ws, size_t ws_size,
                              hipStream_t stream) {
    const float* samples = (const float*)d_in[0];
    const float* w_ih    = (const float*)d_in[1];
    const float* w_hh    = (const float*)d_in[2];
    const float* b_ih    = (const float*)d_in[3];
    const float* b_hh    = (const float*)d_in[4];
    const float* fc_w    = (const float*)d_in[5];
    const float* fc_b    = (const float*)d_in[6];
    float* out  = (float*)d_out;
    ull*   hrep = (ull*)d_ws;    // [8][2][1024] tagged slots = 128KB

    // seed every replica: parity-0 = h0 (zeros, tag 0); parity-1 = sentinel
    hipLaunchKernelGGL(init_hrep_kernel, dim3(64), dim3(256), 0, stream, hrep);

    (void)hipFuncSetAttribute((const void*)gru_persistent_kernel,
                              hipFuncAttributeMaxDynamicSharedMemorySize, LDS_BYTES);

    void* args[] = {(void*)&samples, (void*)&w_ih, (void*)&w_hh, (void*)&b_ih,
                    (void*)&b_hh, (void*)&fc_w, (void*)&fc_b,
                    (void*)&out, (void*)&hrep};
    hipError_t rc = hipLaunchCooperativeKernel(
        reinterpret_cast<void*>(gru_persistent_kernel),
        dim3(G), dim3(WGSIZE), args, LDS_BYTES, stream);
    if (rc != hipSuccess) {
        hipLaunchKernelGGL(gru_persistent_kernel, dim3(G), dim3(WGSIZE), LDS_BYTES, stream,
                           samples, w_ih, w_hh, b_ih, b_hh, fc_w, fc_b, out, hrep);
    }
}

// Round 14
// 28328.299 us; speedup vs baseline: 1.5749x; 1.0361x over previous
//
#include <hip/hip_runtime.h>
#include <cstdint>
#include <cstddef>

#define H        2048
#define T_STEPS  16384
#define G        256     // workgroups == CUs, 1 WG/CU
#define HC       8       // h indices per WG (H/G)
#define WGSIZE   256
#define NREP     8       // mailbox replicas: reader WG g polls replica g&7

// ---- LDS layout (bytes): weights in VGPRs, samples in LDS, no h16 buffer ----
#define LDS_S_OFF    0                         // float2 samples[16384] = 128KB
#define LDS_RED_OFF  131072                    // float red[8]
#define LDS_BYTES    (131072 + 32)             // 131104 < 160KB

typedef unsigned long long ull;
typedef unsigned int uv4 __attribute__((ext_vector_type(4)));
typedef _Float16 half2_ __attribute__((ext_vector_type(2)));

__device__ __forceinline__ float sigmoidf_(float x) {
    return 1.0f / (1.0f + __expf(-x));
}
__device__ __forceinline__ float tanhf_(float x) {
    return 1.0f - 2.0f / (__expf(2.0f * x) + 1.0f);
}
__device__ __forceinline__ uint32_t pack_f16x2(float a, float b) {
    _Float16 ha = (_Float16)a, hb = (_Float16)b;
    return (uint32_t)__builtin_bit_cast(uint16_t, ha)
         | ((uint32_t)__builtin_bit_cast(uint16_t, hb) << 16);
}
__device__ __forceinline__ float f16lo(uint32_t d) {
    return (float)__builtin_bit_cast(_Float16, (uint16_t)(d & 0xFFFFu));
}
__device__ __forceinline__ float f16hi(uint32_t d) {
    return (float)__builtin_bit_cast(_Float16, (uint16_t)(d >> 16));
}
__device__ __forceinline__ float dot2f(uint32_t w, uint32_t h, float acc) {
#if __has_builtin(__builtin_amdgcn_fdot2)
    return __builtin_amdgcn_fdot2(__builtin_bit_cast(half2_, w),
                                  __builtin_bit_cast(half2_, h), acc, false);
#else
    return acc + f16lo(w) * f16lo(h) + f16hi(w) * f16hi(h);
#endif
}

// ---- DPP wave-sum (rocPRIM pattern): 6 VALU adds, total lands in lane 63 ----
template <int CTRL, int ROW_MASK>
__device__ __forceinline__ float dpp_add(float x) {
    int xi = __builtin_bit_cast(int, x);
    int s  = __builtin_amdgcn_update_dpp(0, xi, CTRL, ROW_MASK, 0xf, true);
    return x + __builtin_bit_cast(float, s);
}
__device__ __forceinline__ float wave_sum_dpp(float x) {
    x = dpp_add<0x111, 0xf>(x);   // row_shr:1
    x = dpp_add<0x112, 0xf>(x);   // row_shr:2
    x = dpp_add<0x114, 0xf>(x);   // row_shr:4
    x = dpp_add<0x118, 0xf>(x);   // row_shr:8  -> lane15/31/47/63 = row sums
    x = dpp_add<0x142, 0xa>(x);   // row_bcast:15 -> lane31=r0+r1, lane63=r2+r3
    x = dpp_add<0x143, 0xc>(x);   // row_bcast:31 -> lane63 = total
    return x;
}
__device__ __forceinline__ float rl63(float x) {
    return __builtin_bit_cast(float,
        __builtin_amdgcn_readlane(__builtin_bit_cast(int, x), 63));
}
__device__ __forceinline__ float rlN(float x, int n) {
    return __builtin_bit_cast(float,
        __builtin_amdgcn_readlane(__builtin_bit_cast(int, x), n));
}
// fold of (tag ^ tu) over the 16 tag words of one 8-load poll round
__device__ __forceinline__ uint32_t tagfold(uv4 a, uv4 b, uv4 c, uv4 d,
                                            uv4 e, uv4 f, uv4 g2, uv4 h2,
                                            uint32_t tu) {
    return (a.y ^ tu) | (a.w ^ tu) | (b.y ^ tu) | (b.w ^ tu)
         | (c.y ^ tu) | (c.w ^ tu) | (d.y ^ tu) | (d.w ^ tu)
         | (e.y ^ tu) | (e.w ^ tu) | (f.y ^ tu) | (f.w ^ tu)
         | (g2.y ^ tu) | (g2.w ^ tu) | (h2.y ^ tu) | (h2.w ^ tu);
}

// hrep layout: [8 replicas][2 parities][1024 slots of {f16x2, u32 tag}] = 128KB
__global__ void init_hrep_kernel(ull* __restrict__ hl) {
    int i = blockIdx.x * 256 + threadIdx.x;            // 0..16383
    int parity = (i >> 10) & 1;
    ull v = (parity == 0) ? 0ull : 0xFFFFFFFF00000000ull;
    __hip_atomic_store(hl + i, v, __ATOMIC_RELAXED, __HIP_MEMORY_SCOPE_AGENT);
}

extern "C" __global__ void __launch_bounds__(WGSIZE, 1)
gru_persistent_kernel(const float* __restrict__ samples,
                      const float* __restrict__ w_ih,
                      const float* __restrict__ w_hh,
                      const float* __restrict__ b_ih,
                      const float* __restrict__ b_hh,
                      const float* __restrict__ fc_w,
                      const float* __restrict__ fc_b,
                      float* __restrict__ out,
                      ull*   __restrict__ hrep)    // [8][2][1024] tagged slots
{
    extern __shared__ char smem[];
    float2*   slds = (float2*)(smem + LDS_S_OFF);      // samples, LDS-resident
    float*    red  = (float*)(smem + LDS_RED_OFF);

    const int g    = blockIdx.x;
    const int tid  = threadIdx.x;
    const int wave = tid >> 6;
    const int lane = tid & 63;
    const int myrep = g & (NREP - 1);   // the replica this WG reads

    // ---- one-time: stage this wave's 6 w_hh rows into VGPRs as f16x2 ----
    uint4 wreg[6][4];
    float4 creg[6];                     // (w_ih0, w_ih1, b_ih, b_hh) per row
#pragma unroll
    for (int qi = 0; qi < 6; ++qi) {
        const int grow = (qi >> 1) * H + g * HC + 2 * wave + (qi & 1);
        const float* wr = w_hh + (size_t)grow * H;
#pragma unroll
        for (int k = 0; k < 4; ++k) {
            const float* s2 = wr + 8 * (lane + 64 * k);
            float4 a = *(const float4*)(s2);
            float4 b = *(const float4*)(s2 + 4);
            uint4 p;
            p.x = pack_f16x2(a.x, a.y);
            p.y = pack_f16x2(a.z, a.w);
            p.z = pack_f16x2(b.x, b.y);
            p.w = pack_f16x2(b.z, b.w);
            wreg[qi][k] = p;
        }
        creg[qi] = make_float4(w_ih[grow * 2 + 0], w_ih[grow * 2 + 1],
                               b_ih[grow], b_hh[grow]);
    }
    {   // one-time: samples -> LDS
        const float4* s4 = (const float4*)samples;
        float4* d4 = (float4*)slds;
        for (int i = tid; i < T_STEPS / 2; i += WGSIZE) d4[i] = s4[i];
    }
    __syncthreads();

    // publish targets: lanes 0-7 each own one replica (single instruction)
    ull* pub_e = hrep + ((size_t)(2 * (lane & 7) + 0) << 10) + g * 4 + wave;  // pn=0
    ull* pub_o = hrep + ((size_t)(2 * (lane & 7) + 1) << 10) + g * 4 + wave;  // pn=1

    // per-parity direct-poll bases: lane's 4 chunks at {0,16,2048,2064} from
    // base and base+4096 (chunk k at lane*32 + k*2048)
    const char* pbase0 = (const char*)(hrep + ((size_t)(myrep * 2 + 0) << 10)) + lane * 32;
    const char* pbase1 = (const char*)(hrep + ((size_t)(myrep * 2 + 1) << 10)) + lane * 32;

    float hloc0 = 0.0f, hloc1 = 0.0f;

    for (int t = 0; t < T_STEPS; ++t) {
        float2 sv = slds[t];
        const int p = t & 1;

        // FIXED pre-poll sleep, 20 notches (~1280 cy) -- the measured optimum.
        // Scan results: sleep20=4216 cy/step, sleep24(slow-compute)=4347,
        // sleep26=4300; curve is flat-bottomed at 20 (below-knee sleep is
        // absorbed into poll wait; above-knee leaks into the period).
        // R12 lesson: no adaptive control (coupled-WG feedback is unstable).
        if (t > 0) __builtin_amdgcn_s_sleep(20);

        // ---- single-round direct 4-chunk poll (R8 structure, verbatim):
        // vmcnt(0) inside the loop -> no in-flight loads survive (no race).
        const char* pb  = p ? pbase1 : pbase0;
        const char* pb2 = pb + 4096;
        const uint32_t tu = (uint32_t)t;
        uv4 c0a, c0b, c1a, c1b, c2a, c2b, c3a, c3b;
        for (;;) {
            asm volatile(
                "global_load_dwordx4 %0, %8, off sc0 sc1\n\t"
                "global_load_dwordx4 %1, %8, off offset:16 sc0 sc1\n\t"
                "global_load_dwordx4 %2, %8, off offset:2048 sc0 sc1\n\t"
                "global_load_dwordx4 %3, %8, off offset:2064 sc0 sc1\n\t"
                "global_load_dwordx4 %4, %9, off sc0 sc1\n\t"
                "global_load_dwordx4 %5, %9, off offset:16 sc0 sc1\n\t"
                "global_load_dwordx4 %6, %9, off offset:2048 sc0 sc1\n\t"
                "global_load_dwordx4 %7, %9, off offset:2064 sc0 sc1\n\t"
                "s_waitcnt vmcnt(0)"
                : "=v"(c0a), "=v"(c0b), "=v"(c1a), "=v"(c1b),
                  "=v"(c2a), "=v"(c2b), "=v"(c3a), "=v"(c3b)
                : "v"(pb), "v"(pb2)
                : "memory");
            uint32_t m = tagfold(c0a, c0b, c1a, c1b, c2a, c2b, c3a, c3b, tu);
            if (m == 0) break;
        }
        // assemble the 4 h-chunks (strip tags: payloads at .x/.z)
        uint4 hq[4];
        hq[0].x = c0a.x; hq[0].y = c0a.z; hq[0].z = c0b.x; hq[0].w = c0b.z;
        hq[1].x = c1a.x; hq[1].y = c1a.z; hq[1].z = c1b.x; hq[1].w = c1b.z;
        hq[2].x = c2a.x; hq[2].y = c2a.z; hq[2].z = c2b.x; hq[2].w = c2b.z;
        hq[3].x = c3a.x; hq[3].y = c3a.z; hq[3].z = c3b.x; hq[3].w = c3b.z;

        float acc[6];
#pragma unroll
        for (int qi = 0; qi < 6; ++qi) {
            float s = 0.0f;
#pragma unroll
            for (int k = 0; k < 4; ++k) {
                const uint4 wv = wreg[qi][k];
                s = dot2f(wv.x, hq[k].x, s);
                s = dot2f(wv.y, hq[k].y, s);
                s = dot2f(wv.z, hq[k].z, s);
                s = dot2f(wv.w, hq[k].w, s);
            }
            acc[qi] = s;
        }

        // ---- DPP reduction: 6 independent 6-op trees (ILP) ----
        float t0 = rl63(wave_sum_dpp(acc[0]));
        float t1 = rl63(wave_sum_dpp(acc[1]));
        float t2 = rl63(wave_sum_dpp(acc[2]));
        float t3 = rl63(wave_sum_dpp(acc[3]));
        float t4 = rl63(wave_sum_dpp(acc[4]));
        float t5 = rl63(wave_sum_dpp(acc[5]));

        // gate tail split across lanes 0/1 (jj = lane); sums are SGPR-uniform
        const bool l0 = (lane == 0);
        float aR = l0 ? t0 : t1;
        float aZ = l0 ? t2 : t3;
        float aN = l0 ? t4 : t5;
        float4 cr = l0 ? creg[0] : creg[1];
        float4 cz = l0 ? creg[2] : creg[3];
        float4 cn = l0 ? creg[4] : creg[5];
        float hold = l0 ? hloc0 : hloc1;
        float xr = sv.x * cr.x + sv.y * cr.y + cr.z;
        float xz = sv.x * cz.x + sv.y * cz.y + cz.z;
        float xn = sv.x * cn.x + sv.y * cn.y + cn.z;
        float r  = sigmoidf_(xr + aR + cr.w);
        float z  = sigmoidf_(xz + aZ + cz.w);
        float n  = tanhf_(xn + r * (aN + cn.w));
        float hn = (1.0f - z) * n + z * hold;    // meaningful in lanes 0,1

        // SALU broadcast (readlane, ~8cy) instead of shfl (ds_bpermute, ~30cy)
        // on the publish-critical path
        float h0n = rlN(hn, 0);
        float h1n = rlN(hn, 1);
        hloc0 = h0n;
        hloc1 = h1n;

        // publish: one agent-scope atomic per replica, lanes 0-7 in parallel
        ull s0 = (ull)pack_f16x2(h0n, h1n) | ((ull)(uint32_t)(t + 1) << 32);
        const int pn = (t + 1) & 1;
        if (lane < 8) {
            ull* pp = pn ? pub_o : pub_e;
            (void)__hip_atomic_exchange(pp, s0, __ATOMIC_RELAXED,
                                        __HIP_MEMORY_SCOPE_AGENT);
        }
        // no barrier anywhere in the step loop
    }

    // ---- epilogue: WG 0 computes sigmoid(h_T . fc_w + fc_b) ----
    if (g == 0) {
        const ull* lp = hrep + ((size_t)(T_STEPS & 1) << 10) + tid * 4;  // replica 0
        const uint32_t tu = (uint32_t)T_STEPS;
        uv4 q0, q1;
        for (;;) {
            asm volatile(
                "global_load_dwordx4 %0, %2, off sc0 sc1\n\t"
                "global_load_dwordx4 %1, %2, off offset:16 sc0 sc1\n\t"
                "s_waitcnt vmcnt(0)"
                : "=v"(q0), "=v"(q1)
                : "v"(lp)
                : "memory");
            if ((q0.y == tu) & (q0.w == tu) & (q1.y == tu) & (q1.w == tu)) break;
            __builtin_amdgcn_s_sleep(2);
        }
        float hv[8];
        hv[0] = f16lo(q0.x); hv[1] = f16hi(q0.x);
        hv[2] = f16lo(q0.z); hv[3] = f16hi(q0.z);
        hv[4] = f16lo(q1.x); hv[5] = f16hi(q1.x);
        hv[6] = f16lo(q1.z); hv[7] = f16hi(q1.z);
        float pacc = 0.0f;
#pragma unroll
        for (int e = 0; e < 8; ++e)
            pacc += hv[e] * fc_w[tid * 8 + e];
#pragma unroll
        for (int off = 32; off > 0; off >>= 1)
            pacc += __shfl_xor(pacc, off, 64);
        if (lane == 0) red[wave] = pacc;
        __syncthreads();
        if (tid == 0) {
            float s = red[0] + red[1] + red[2] + red[3];
            out[0] = sigmoidf_(s + fc_b[0]);
        }
    }
}

extern "C" void kernel_launch(void* const* d_in, const int* in_sizes, int n_in,
                              void* d_out, int out_size, void* d_ws, size_t ws_size,
                              hipStream_t stream) {
    const float* samples = (const float*)d_in[0];
    const float* w_ih    = (const float*)d_in[1];
    const float* w_hh    = (const float*)d_in[2];
    const float* b_ih    = (const float*)d_in[3];
    const float* b_hh    = (const float*)d_in[4];
    const float* fc_w    = (const float*)d_in[5];
    const float* fc_b    = (const float*)d_in[6];
    float* out  = (float*)d_out;
    ull*   hrep = (ull*)d_ws;    // [8][2][1024] tagged slots = 128KB

    // seed every replica: parity-0 = h0 (zeros, tag 0); parity-1 = sentinel
    hipLaunchKernelGGL(init_hrep_kernel, dim3(64), dim3(256), 0, stream, hrep);

    (void)hipFuncSetAttribute((const void*)gru_persistent_kernel,
                              hipFuncAttributeMaxDynamicSharedMemorySize, LDS_BYTES);

    void* args[] = {(void*)&samples, (void*)&w_ih, (void*)&w_hh, (void*)&b_ih,
                    (void*)&b_hh, (void*)&fc_w, (void*)&fc_b,
                    (void*)&out, (void*)&hrep};
    hipError_t rc = hipLaunchCooperativeKernel(
        reinterpret_cast<void*>(gru_persistent_kernel),
        dim3(G), dim3(WGSIZE), args, LDS_BYTES, stream);
    if (rc != hipSuccess) {
        hipLaunchKernelGGL(gru_persistent_kernel, dim3(G), dim3(WGSIZE), LDS_BYTES, stream,
                           samples, w_ih, w_hh, b_ih, b_hh, fc_w, fc_b, out, hrep);
    }
}